// Round 1
// baseline (488.312 us; speedup 1.0000x reference)
//
#include <hip/hip_runtime.h>
#include <math.h>

#define BS 16
#define M  16
#define T  32
#define V  12000
#define P  64
#define PV 20

#define NCAP   (BS * M * T)     // 8192 caption-token rows
#define NV4    (V / 4)          // 3000 float4 per row
#define CAPB   (NCAP / 4)       // 2048 caption blocks, one row per wave (4 waves/block)
#define NPROGB 4                // 4 blocks x 256 threads = 1024 program rows

// ---------------------------------------------------------------------------
// Fused kernel:
//   blocks [0, CAPB)           : caption CE, ONE ROW PER WAVE (64 lanes).
//                                No LDS, no barriers. Wave-uniform early exit
//                                for masked rows (final kernel recomputes the
//                                mask and skips poisoned ws slots).
//   blocks [CAPB, CAPB+NPROGB) : program CE, 256 rows/block, block-reduced.
// ---------------------------------------------------------------------------
__global__ __launch_bounds__(256) void fused_loss_kernel(
    const float* __restrict__ pred_cap,    // [BS,M,T,V]
    const int*   __restrict__ gt_cap,      // [BS,M,T]
    const int*   __restrict__ cap_lens,    // [BS,M]
    const int*   __restrict__ caps_count,  // [BS]
    const float* __restrict__ pred_prog,   // [BS,P,PV]
    const int*   __restrict__ gt_prog,     // [BS,P]
    const int*   __restrict__ prog_len,    // [BS]
    float*       __restrict__ ws)          // [NCAP + NPROGB] partials
{
    const int bid = blockIdx.x;

    if (bid < CAPB) {
        // ---- caption CE: one row per wave ----
        const int wave = threadIdx.x >> 6;
        const int lane = threadIdx.x & 63;
        const int row  = (bid << 2) + wave;      // 0..8191
        const int t    = row & (T - 1);
        const int bm   = row >> 5;               // row / T
        const int m    = bm & (M - 1);
        const int b    = bm >> 4;                // bm / M
        if (t >= cap_lens[bm] || m >= caps_count[b]) return;  // wave-uniform

        const size_t base = (size_t)row * V;
        // gt logit: issued early, latency hidden under the streaming loop
        const float xg = pred_cap[base + gt_cap[row]];
        const float4* __restrict__ p4 = (const float4*)(pred_cap + base);

        float lmax = -INFINITY, lsum = 0.0f;
        for (int i = lane; i < NV4; i += 64) {
            float4 x = p4[i];
            float m4 = fmaxf(fmaxf(x.x, x.y), fmaxf(x.z, x.w));
            float nm = fmaxf(lmax, m4);
            lsum = lsum * __expf(lmax - nm)
                 + __expf(x.x - nm) + __expf(x.y - nm)
                 + __expf(x.z - nm) + __expf(x.w - nm);
            lmax = nm;
        }
        // 64-lane online-softmax butterfly merge (lane 0 ends correct)
        for (int off = 32; off > 0; off >>= 1) {
            float om = __shfl_down(lmax, off, 64);
            float os = __shfl_down(lsum, off, 64);
            float nm = fmaxf(lmax, om);
            lsum = lsum * __expf(lmax - nm) + os * __expf(om - nm);
            lmax = nm;
        }
        if (lane == 0) ws[row] = logf(lsum) + lmax - xg;  // -(xg - lmax - log(sum))
    } else {
        // ---- program CE: 256 rows per block, one row per thread ----
        __shared__ float ss[4];
        const int pb  = bid - CAPB;                // 0..3
        const int idx = pb * 256 + threadIdx.x;    // 0..1023 == b*P + p
        const int p   = idx % P;
        const int b   = idx / P;

        float nll = 0.0f;
        if (p < prog_len[b]) {
            const float* row = pred_prog + (size_t)idx * PV;
            float mx = row[0];
            #pragma unroll
            for (int i = 1; i < PV; i++) mx = fmaxf(mx, row[i]);
            float s = 0.0f;
            #pragma unroll
            for (int i = 0; i < PV; i++) s += __expf(row[i] - mx);
            nll = logf(s) + mx - row[gt_prog[idx]];
        }
        for (int off = 32; off > 0; off >>= 1) nll += __shfl_down(nll, off, 64);
        const int wave = threadIdx.x >> 6, lane = threadIdx.x & 63;
        if (lane == 0) ss[wave] = nll;
        __syncthreads();
        if (threadIdx.x == 0)
            ws[NCAP + pb] = ss[0] + ss[1] + ss[2] + ss[3];
    }
}

// ---------------------------------------------------------------------------
// Final kernel (1 block, 256 threads): masked sum of cap partials (mask
// recomputed -> poisoned slots skipped), prog partial sum, IoU, ragged
// counts, divisions, 4 outputs.
// ---------------------------------------------------------------------------
__global__ __launch_bounds__(256) void final_kernel(
    const int*   __restrict__ cap_lens,     // [BS,M]
    const int*   __restrict__ caps_count,   // [BS]
    const int*   __restrict__ prog_len,     // [BS]
    const float* __restrict__ gt_iv,        // [BS,M,2]
    const float* __restrict__ pred_iv,      // [BS,M,2]
    const float* __restrict__ ws,           // partials
    float*       __restrict__ out)          // [loss, cap, prog, iou]
{
    const int tid = threadIdx.x;            // also == b*M + m for per-caption work
    __shared__ int   s_len[BS * M];
    __shared__ int   s_cc[BS];
    __shared__ float red[6][256];

    s_len[tid] = cap_lens[tid];
    if (tid < BS) s_cc[tid] = caps_count[tid];
    __syncthreads();

    // masked sum of caption partials: 32 strided rows per thread
    float cap_sum = 0.0f;
    #pragma unroll
    for (int k = 0; k < NCAP / 256; k++) {
        const int r  = tid + k * 256;
        const int t  = r % T;
        const int bm = r / T;
        const int m  = bm % M;
        const int b  = bm / M;
        if (t < s_len[bm] && m < s_cc[b]) cap_sum += ws[r];
    }
    float prog_sum = (tid < NPROGB) ? ws[NCAP + tid] : 0.0f;

    // per-caption token count + IoU  (tid == b*M + m)
    const int m = tid % M, b = tid / M;
    const bool cvalid = (m < s_cc[b]);
    float ntok = cvalid ? (float)s_len[tid] : 0.0f;
    float iou = 0.0f;
    if (cvalid) {
        const float gs = gt_iv[tid * 2], ge = gt_iv[tid * 2 + 1];
        const float ps = pred_iv[tid * 2], pe = pred_iv[tid * 2 + 1];
        float inter = fmaxf(fminf(pe, ge) - fmaxf(ps, gs), 0.0f);
        const float uni = fmaxf(pe, ge) - fminf(ps, gs);
        iou = inter / fmaxf(uni, 1e-8f);
    }
    float nprog = (tid < BS) ? (float)prog_len[tid] : 0.0f;
    float ncaps = (tid < BS) ? (float)s_cc[tid]     : 0.0f;

    red[0][tid] = cap_sum; red[1][tid] = prog_sum; red[2][tid] = ntok;
    red[3][tid] = iou;     red[4][tid] = nprog;    red[5][tid] = ncaps;
    __syncthreads();
    for (int off = 128; off > 0; off >>= 1) {
        if (tid < off) {
            #pragma unroll
            for (int q = 0; q < 6; q++) red[q][tid] += red[q][tid + off];
        }
        __syncthreads();
    }
    if (tid == 0) {
        const float cap_loss  = red[0][0] / fmaxf(red[2][0], 1.0f);
        const float prog_loss = red[1][0] / fmaxf(red[4][0], 1.0f);
        const float iou_loss  = 1.0f - red[3][0] / fmaxf(red[5][0], 1.0f);
        out[0] = cap_loss + prog_loss;
        out[1] = cap_loss;
        out[2] = prog_loss;
        out[3] = iou_loss;
    }
}

extern "C" void kernel_launch(void* const* d_in, const int* in_sizes, int n_in,
                              void* d_out, int out_size, void* d_ws, size_t ws_size,
                              hipStream_t stream) {
    const int*   gt_captions    = (const int*)  d_in[0];
    const int*   gt_cap_lens    = (const int*)  d_in[1];
    const float* pred_captions  = (const float*)d_in[2];
    const int*   gt_program     = (const int*)  d_in[3];
    const int*   gt_prog_len    = (const int*)  d_in[4];
    const float* pred_program   = (const float*)d_in[5];
    const float* gt_intervals   = (const float*)d_in[6];
    const float* pred_intervals = (const float*)d_in[7];
    const int*   gt_caps_count  = (const int*)  d_in[8];
    // d_in[9] (pred_caps_count) unused by the reference math.

    float* ws  = (float*)d_ws;
    float* out = (float*)d_out;

    fused_loss_kernel<<<CAPB + NPROGB, 256, 0, stream>>>(
        pred_captions, gt_captions, gt_cap_lens, gt_caps_count,
        pred_program, gt_program, gt_prog_len, ws);

    final_kernel<<<1, 256, 0, stream>>>(
        gt_cap_lens, gt_caps_count, gt_prog_len,
        gt_intervals, pred_intervals, ws, out);
}